// Round 12
// baseline (1277.346 us; speedup 1.0000x reference)
//
#include <hip/hip_runtime.h>
#include <hip/hip_fp16.h>

// Instant-NGP grid encoder, MI355X (gfx950).
// N=2,000,000 points [N,3] f32 in [0,1); 12 levels, F=2; out [N,24] f32.
// res: 16,23,32,46,64,92,128,184,256,368,512,736; hash iff r^3>2^19
// (levels 5..11, each exactly 2^19 entries -> & 0x7FFFF). Dense: no modulo.
//
// Round-12: round-10 structure (best measured: mega=455us) with ONE new
// variable: NON-TEMPORAL TABLE GATHERS (L1 bypass).
//   Elimination so far: not VALU (12%), not HBM (9%), not occupancy (90%),
//   not per-thread MLP (PPT=4 null, r11), not L3 retention (cacheable stage
//   made FETCH worse, r11). Remaining: L1 64B line-fill amplification on
//   ~108M random gathers (8-16B used per 64B fill = 6.9GB L1<-L2 traffic).
//   nt gather loads skip TCP allocation. Reverts: hash PPT=2, nt stage
//   stores (round-10 config).

namespace {
constexpr int NLEV = 12;
constexpr int BLOCK = 256;
constexpr int DENSE_A_END = 146368;   // levels 0..3
constexpr int L4_SIZE = 262144;       // level 4 (64^3)
constexpr unsigned P1 = 2654435761u;
constexpr unsigned P2 = 805459861u;
constexpr unsigned HMASK = (1u << 19) - 1u;

__device__ __constant__ constexpr int kRes[NLEV] = {
    16, 23, 32, 46, 64, 92, 128, 184, 256, 368, 512, 736};
__device__ __constant__ constexpr int kOff[NLEV] = {
    0, 4096, 16264, 49032, 146368, 408512,
    932800, 1457088, 1981376, 2505664, 3029952, 3554240};

typedef float    f32x2 __attribute__((ext_vector_type(2)));
typedef unsigned u32x2 __attribute__((ext_vector_type(2)));
typedef unsigned u32x4 __attribute__((ext_vector_type(4)));

__device__ __forceinline__ unsigned pkh2(float a, float b) {
    __half2 h = __floats2half2_rn(a, b);
    return *reinterpret_cast<unsigned*>(&h);
}
__device__ __forceinline__ float lo2f(unsigned u) {
    __half2 h = *reinterpret_cast<__half2*>(&u);
    return __low2float(h);
}
__device__ __forceinline__ float hi2f(unsigned u) {
    __half2 h = *reinterpret_cast<__half2*>(&u);
    return __high2float(h);
}
}  // namespace

// ---- fused pre-pass: packed (all), quad (levels 0-3), pair4 (level 4) ----
__global__ void __launch_bounds__(BLOCK)
pack_all_kernel(const float2* __restrict__ emb,
                unsigned* __restrict__ packed,
                u32x4* __restrict__ quad,
                u32x2* __restrict__ pair4, int total)
{
    int i = blockIdx.x * BLOCK + threadIdx.x;
    if (i >= total) return;
    float2 v = emb[i];
    packed[i] = pkh2(v.x, v.y);
    if (i < DENSE_A_END) {
        int R = (i < 4096) ? 16 : (i < 16264) ? 23 : (i < 49032) ? 32 : 46;
        float2 e1 = emb[i + 1];
        float2 e2 = emb[i + R];
        float2 e3 = emb[i + R + 1];
        u32x4 q;
        q.x = pkh2(v.x, v.y);   q.y = pkh2(e1.x, e1.y);
        q.z = pkh2(e2.x, e2.y); q.w = pkh2(e3.x, e3.y);
        quad[i] = q;
    }
    if (i < L4_SIZE) {
        int g = DENSE_A_END + i;
        float2 a = emb[g];
        float2 b = emb[g + 1];
        u32x2 o; o.x = pkh2(a.x, a.y); o.y = pkh2(b.x, b.y);
        pair4[i] = o;
    }
}

// ---- hash level encode, runtime scale; pt pre-offset; nt gathers ----
__device__ __forceinline__ unsigned
encode_hash_rt(float x, float y, float z, const unsigned* __restrict__ pt,
               float scale)
{
    const float px = x * scale, py = y * scale, pz = z * scale;
    const float fx = floorf(px), fy = floorf(py), fz = floorf(pz);
    const float rx = px - fx, ry = py - fy, rz = pz - fz;
    const unsigned ix = (unsigned)fx, iy = (unsigned)fy, iz = (unsigned)fz;
    const unsigned yA = iy * P1, yB = yA + P1;
    const unsigned zA = iz * P2, zB = zA + P2;
    const unsigned h00 = (ix ^ yA ^ zA) & HMASK;
    const unsigned h10 = (ix ^ yB ^ zA) & HMASK;
    const unsigned h01 = (ix ^ yA ^ zB) & HMASK;
    const unsigned h11 = (ix ^ yB ^ zB) & HMASK;

    const u32x2* pt2 = reinterpret_cast<const u32x2*>(pt);
    const u32x2 q00 = __builtin_nontemporal_load(&pt2[h00 >> 1]);
    const u32x2 q10 = __builtin_nontemporal_load(&pt2[h10 >> 1]);
    const u32x2 q01 = __builtin_nontemporal_load(&pt2[h01 >> 1]);
    const u32x2 q11 = __builtin_nontemporal_load(&pt2[h11 >> 1]);

    unsigned e00 = (h00 & 1) ? q00.y : q00.x;
    unsigned e10 = (h10 & 1) ? q10.y : q10.x;
    unsigned e01 = (h01 & 1) ? q01.y : q01.x;
    unsigned e11 = (h11 & 1) ? q11.y : q11.x;
    unsigned f00 = (h00 & 1) ? q00.x : q00.y;
    unsigned f10 = (h10 & 1) ? q10.x : q10.y;
    unsigned f01 = (h01 & 1) ? q01.x : q01.y;
    unsigned f11 = (h11 & 1) ? q11.x : q11.y;

    if (ix & 1u) {  // odd ix: sibling word is ix-1; need real ix+1 entries
        const unsigned xo = ix + 1u;
        f00 = __builtin_nontemporal_load(&pt[(xo ^ yA ^ zA) & HMASK]);
        f10 = __builtin_nontemporal_load(&pt[(xo ^ yB ^ zA) & HMASK]);
        f01 = __builtin_nontemporal_load(&pt[(xo ^ yA ^ zB) & HMASK]);
        f11 = __builtin_nontemporal_load(&pt[(xo ^ yB ^ zB) & HMASK]);
    }

    const float wx0 = 1.0f - rx, wx1 = rx;
    const float wy0 = 1.0f - ry, wy1 = ry;
    const float wz0 = 1.0f - rz, wz1 = rz;
    const float w00 = wy0 * wz0, w10 = wy1 * wz0;
    const float w01 = wy0 * wz1, w11 = wy1 * wz1;
    float sx = 0.0f, sy = 0.0f;
    sx = fmaf(w00 * wx0, lo2f(e00), fmaf(w00 * wx1, lo2f(f00), sx));
    sy = fmaf(w00 * wx0, hi2f(e00), fmaf(w00 * wx1, hi2f(f00), sy));
    sx = fmaf(w10 * wx0, lo2f(e10), fmaf(w10 * wx1, lo2f(f10), sx));
    sy = fmaf(w10 * wx0, hi2f(e10), fmaf(w10 * wx1, hi2f(f10), sy));
    sx = fmaf(w01 * wx0, lo2f(e01), fmaf(w01 * wx1, lo2f(f01), sx));
    sy = fmaf(w01 * wx0, hi2f(e01), fmaf(w01 * wx1, hi2f(f01), sy));
    sx = fmaf(w11 * wx0, lo2f(e11), fmaf(w11 * wx1, lo2f(f11), sx));
    sy = fmaf(w11 * wx0, hi2f(e11), fmaf(w11 * wx1, hi2f(f11), sy));
    return pkh2(sx, sy);
}

// ---- MEGA: blocks [0,CB)=dense_a, [CB,2CB)=dense_b, [2CB,9CB)=hash5..11 ----
__global__ void __launch_bounds__(BLOCK)
mega_kernel(const float* __restrict__ inp,
            const u32x4* __restrict__ quad,
            const u32x2* __restrict__ pair4,
            const unsigned* __restrict__ packed,
            unsigned* __restrict__ stage, int N, int CB)
{
    const int b = blockIdx.x;
    const int t = b / CB;            // task id (block-uniform)
    const int chunk = b - t * CB;
    const int g = chunk * BLOCK + threadIdx.x;   // point-pair index
    const int p0 = 2 * g;
    if (p0 >= N) return;
    const bool two = (p0 + 1 < N);

    const f32x2* ip2 = reinterpret_cast<const f32x2*>(inp);
    f32x2 v0 = ip2[3 * g + 0];
    f32x2 v1, v2;
    if (two) { v1 = ip2[3 * g + 1]; v2 = ip2[3 * g + 2]; }
    else { v1.x = inp[3 * p0 + 2]; v1.y = 0.f; v2.x = 0.f; v2.y = 0.f; }
    const float X[2] = {v0.x, v1.y};
    const float Y[2] = {v0.y, v2.x};
    const float Z[2] = {v1.x, v2.y};

    if (t == 0) {
        // dense levels 0..3, quad nt gathers
#pragma unroll
        for (int l = 0; l < 4; ++l) {
            const unsigned R = (unsigned)kRes[l];
            const unsigned R2 = R * R;
            const float scale = (float)(kRes[l] - 1);
            const u32x4* qt = quad + kOff[l];
            u32x2 res;
#pragma unroll
            for (int k = 0; k < 2; ++k) {
                const float px = X[k] * scale, py = Y[k] * scale,
                            pz = Z[k] * scale;
                const float fx = floorf(px), fy = floorf(py), fz = floorf(pz);
                const float rx = px - fx, ry = py - fy, rz = pz - fz;
                const unsigned ix = (unsigned)fx, iy = (unsigned)fy,
                               iz = (unsigned)fz;
                const unsigned base = ix + iy * R + iz * R2;
                const u32x4 q0 = __builtin_nontemporal_load(&qt[base]);
                const u32x4 q1 = __builtin_nontemporal_load(&qt[base + R2]);
                const float wx0 = 1.0f - rx, wx1 = rx;
                const float wy0 = 1.0f - ry, wy1 = ry;
                const float wz0 = 1.0f - rz, wz1 = rz;
                const float ex00 = wx0 * lo2f(q0.x) + wx1 * lo2f(q0.y);
                const float ey00 = wx0 * hi2f(q0.x) + wx1 * hi2f(q0.y);
                const float ex10 = wx0 * lo2f(q0.z) + wx1 * lo2f(q0.w);
                const float ey10 = wx0 * hi2f(q0.z) + wx1 * hi2f(q0.w);
                const float ex01 = wx0 * lo2f(q1.x) + wx1 * lo2f(q1.y);
                const float ey01 = wx0 * hi2f(q1.x) + wx1 * hi2f(q1.y);
                const float ex11 = wx0 * lo2f(q1.z) + wx1 * lo2f(q1.w);
                const float ey11 = wx0 * hi2f(q1.z) + wx1 * hi2f(q1.w);
                const float sx = wz0 * (wy0 * ex00 + wy1 * ex10) +
                                 wz1 * (wy0 * ex01 + wy1 * ex11);
                const float sy = wz0 * (wy0 * ey00 + wy1 * ey10) +
                                 wz1 * (wy0 * ey01 + wy1 * ey11);
                res[k] = pkh2(sx, sy);
            }
            if (two) {
                __builtin_nontemporal_store(
                    res,
                    reinterpret_cast<u32x2*>(&stage[(long long)l * N + p0]));
            } else {
                __builtin_nontemporal_store(res.x,
                                            &stage[(long long)l * N + p0]);
            }
        }
    } else if (t == 1) {
        // dense level 4 (64^3), pair nt gathers
        constexpr unsigned R = 64, R2 = 4096;
        constexpr float scale = 63.0f;
        u32x2 res;
#pragma unroll
        for (int k = 0; k < 2; ++k) {
            const float px = X[k] * scale, py = Y[k] * scale, pz = Z[k] * scale;
            const float fx = floorf(px), fy = floorf(py), fz = floorf(pz);
            const float rx = px - fx, ry = py - fy, rz = pz - fz;
            const unsigned ix = (unsigned)fx, iy = (unsigned)fy,
                           iz = (unsigned)fz;
            const unsigned base = ix + iy * R + iz * R2;
            const u32x2 q00 = __builtin_nontemporal_load(&pair4[base]);
            const u32x2 q10 = __builtin_nontemporal_load(&pair4[base + R]);
            const u32x2 q01 = __builtin_nontemporal_load(&pair4[base + R2]);
            const u32x2 q11 = __builtin_nontemporal_load(&pair4[base + R2 + R]);
            const float wx0 = 1.0f - rx, wx1 = rx;
            const float wy0 = 1.0f - ry, wy1 = ry;
            const float wz0 = 1.0f - rz, wz1 = rz;
            const float w00 = wy0 * wz0, w10 = wy1 * wz0;
            const float w01 = wy0 * wz1, w11 = wy1 * wz1;
            float sx = 0.0f, sy = 0.0f;
            sx = fmaf(w00 * wx0, lo2f(q00.x), fmaf(w00 * wx1, lo2f(q00.y), sx));
            sy = fmaf(w00 * wx0, hi2f(q00.x), fmaf(w00 * wx1, hi2f(q00.y), sy));
            sx = fmaf(w10 * wx0, lo2f(q10.x), fmaf(w10 * wx1, lo2f(q10.y), sx));
            sy = fmaf(w10 * wx0, hi2f(q10.x), fmaf(w10 * wx1, hi2f(q10.y), sy));
            sx = fmaf(w01 * wx0, lo2f(q01.x), fmaf(w01 * wx1, lo2f(q01.y), sx));
            sy = fmaf(w01 * wx0, hi2f(q01.x), fmaf(w01 * wx1, hi2f(q01.y), sy));
            sx = fmaf(w11 * wx0, lo2f(q11.x), fmaf(w11 * wx1, lo2f(q11.y), sx));
            sy = fmaf(w11 * wx0, hi2f(q11.x), fmaf(w11 * wx1, hi2f(q11.y), sy));
            res[k] = pkh2(sx, sy);
        }
        unsigned* s4 = stage + 4LL * N;
        if (two) {
            __builtin_nontemporal_store(res, reinterpret_cast<u32x2*>(&s4[p0]));
        } else {
            __builtin_nontemporal_store(res.x, &s4[p0]);
        }
    } else {
        // hash level L = t + 3 (t=2..8 -> L=5..11)
        const int L = t + 3;
        const float scale = (float)(kRes[L] - 1);
        const unsigned* pt = packed + kOff[L];
        u32x2 res;
        res.x = encode_hash_rt(X[0], Y[0], Z[0], pt, scale);
        res.y = two ? encode_hash_rt(X[1], Y[1], Z[1], pt, scale) : 0u;
        unsigned* sl = stage + (long long)L * N;
        if (two) {
            __builtin_nontemporal_store(res, reinterpret_cast<u32x2*>(&sl[p0]));
        } else {
            __builtin_nontemporal_store(res.x, &sl[p0]);
        }
    }
}

// ---- final: [12][N] fp16x2 -> [N][24] f32, LDS transpose ----
__global__ void __launch_bounds__(BLOCK)
assemble_kernel(const unsigned* __restrict__ lvl, float* __restrict__ out,
                int N)
{
    __shared__ float s_out[BLOCK * 25];
    const int t = threadIdx.x;
    const int n = blockIdx.x * BLOCK + t;

    if (n < N) {
#pragma unroll
        for (int l = 0; l < NLEV; ++l) {
            unsigned u = __builtin_nontemporal_load(&lvl[(long long)l * N + n]);
            s_out[t * 25 + 2 * l + 0] = lo2f(u);
            s_out[t * 25 + 2 * l + 1] = hi2f(u);
        }
    }
    __syncthreads();

    const long long base = (long long)blockIdx.x * (BLOCK * 24);
    const long long lim = (long long)N * 24;
#pragma unroll
    for (int k = 0; k < 24; ++k) {
        const int g = k * BLOCK + t;
        const long long gg = base + g;
        if (gg < lim) {
            const int nl = g / 24;   // magic-mul division
            const int j = g - nl * 24;
            __builtin_nontemporal_store(s_out[nl * 25 + j], &out[gg]);
        }
    }
}

// ---- fallback: fused single-kernel (ws too small for staging) ----
__global__ void __launch_bounds__(BLOCK, 4)
fused_kernel(const float* __restrict__ inp, const float2* __restrict__ table,
             float* __restrict__ out, int N)
{
    __shared__ float s_out[BLOCK * 25];
    const int t = threadIdx.x;
    const int n = blockIdx.x * BLOCK + t;

    if (n < N) {
        const float x = inp[n * 3 + 0];
        const float y = inp[n * 3 + 1];
        const float z = inp[n * 3 + 2];

#pragma unroll
        for (int l = 0; l < NLEV; ++l) {
            const int R = kRes[l];
            const bool HASH = (l >= 5);
            const float scale = (float)(R - 1);
            const float px = x * scale, py = y * scale, pz = z * scale;
            const float fx = floorf(px), fy = floorf(py), fz = floorf(pz);
            const float wx = px - fx, wy = py - fy, wz = pz - fz;
            const unsigned ix = (unsigned)fx, iy = (unsigned)fy,
                           iz = (unsigned)fz;
            unsigned x0, x1, y0, y1, z0, z1;
            if (HASH) {
                x0 = ix;      x1 = ix + 1u;
                y0 = iy * P1; y1 = y0 + P1;
                z0 = iz * P2; z1 = z0 + P2;
            } else {
                const unsigned Ru = (unsigned)R, R2 = Ru * Ru;
                x0 = ix;      x1 = ix + 1u;
                y0 = iy * Ru; y1 = y0 + Ru;
                z0 = iz * R2; z1 = z0 + R2;
            }
            unsigned idx[8];
            if (HASH) {
                idx[0] = (x0 ^ y0 ^ z0) & HMASK; idx[1] = (x1 ^ y0 ^ z0) & HMASK;
                idx[2] = (x0 ^ y1 ^ z0) & HMASK; idx[3] = (x1 ^ y1 ^ z0) & HMASK;
                idx[4] = (x0 ^ y0 ^ z1) & HMASK; idx[5] = (x1 ^ y0 ^ z1) & HMASK;
                idx[6] = (x0 ^ y1 ^ z1) & HMASK; idx[7] = (x1 ^ y1 ^ z1) & HMASK;
            } else {
                idx[0] = x0 + y0 + z0; idx[1] = x1 + y0 + z0;
                idx[2] = x0 + y1 + z0; idx[3] = x1 + y1 + z0;
                idx[4] = x0 + y0 + z1; idx[5] = x1 + y0 + z1;
                idx[6] = x0 + y1 + z1; idx[7] = x1 + y1 + z1;
            }
            const float w0x = 1.0f - wx, w0y = 1.0f - wy, w0z = 1.0f - wz;
            const float w00 = w0x * w0y, w10 = wx * w0y;
            const float w01 = w0x * wy,  w11 = wx * wy;
            const float wt[8] = {w00 * w0z, w10 * w0z, w01 * w0z, w11 * w0z,
                                 w00 * wz,  w10 * wz,  w01 * wz,  w11 * wz};
            float sx = 0.0f, sy = 0.0f;
#pragma unroll
            for (int c = 0; c < 8; ++c) {
                float2 e = table[kOff[l] + idx[c]];
                sx = fmaf(wt[c], e.x, sx);
                sy = fmaf(wt[c], e.y, sy);
            }
            s_out[t * 25 + 2 * l + 0] = sx;
            s_out[t * 25 + 2 * l + 1] = sy;
        }
    }
    __syncthreads();
    const long long base = (long long)blockIdx.x * (BLOCK * 24);
    const long long lim = (long long)N * 24;
#pragma unroll
    for (int k = 0; k < 24; ++k) {
        const int g = k * BLOCK + t;
        const long long gg = base + g;
        if (gg < lim) {
            const int nl = g / 24;
            const int j = g - nl * 24;
            out[gg] = s_out[nl * 25 + j];
        }
    }
}

extern "C" void kernel_launch(void* const* d_in, const int* in_sizes, int n_in,
                              void* d_out, int out_size, void* d_ws, size_t ws_size,
                              hipStream_t stream) {
    const float* inputs = (const float*)d_in[0];
    const float* embeddings = (const float*)d_in[1];
    // d_in[2]/d_in[3] (offsets/resolutions) are compile-time constants here.
    float* out = (float*)d_out;

    const int N = in_sizes[0] / 3;            // 2,000,000
    const int total = in_sizes[1] / 2;        // 4,078,528 table entries

    const size_t quad_bytes = (size_t)DENSE_A_END * 16;           // 2.34 MB
    const size_t pair4_bytes = (size_t)L4_SIZE * 8;               // 2.0 MB
    const size_t packed_bytes = (size_t)total * sizeof(unsigned); // 16.3 MB
    const size_t stage_bytes = (size_t)NLEV * N * sizeof(unsigned); // 96 MB

    const int ngrid = (N + BLOCK - 1) / BLOCK;

    if (ws_size >= quad_bytes + pair4_bytes + packed_bytes + stage_bytes) {
        char* w = (char*)d_ws;
        u32x4* quad = (u32x4*)w;                  w += quad_bytes;
        u32x2* pair4 = (u32x2*)w;                 w += pair4_bytes;
        unsigned* packed = (unsigned*)w;          w += packed_bytes;
        unsigned* stage = (unsigned*)w;

        pack_all_kernel<<<(total + BLOCK - 1) / BLOCK, BLOCK, 0, stream>>>(
            (const float2*)embeddings, packed, quad, pair4, total);

        const int pairs = (N + 1) / 2;
        const int CB = (pairs + BLOCK - 1) / BLOCK;   // chunks per task
        mega_kernel<<<9 * CB, BLOCK, 0, stream>>>(
            inputs, quad, pair4, packed, stage, N, CB);

        assemble_kernel<<<ngrid, BLOCK, 0, stream>>>(stage, out, N);
    } else {
        fused_kernel<<<ngrid, BLOCK, 0, stream>>>(
            inputs, (const float2*)embeddings, out, N);
    }
}

// Round 13
// 487.093 us; speedup vs baseline: 2.6224x; 2.6224x over previous
//
#include <hip/hip_runtime.h>
#include <hip/hip_fp16.h>

// Instant-NGP grid encoder, MI355X (gfx950).
// N=2,000,000 points [N,3] f32 in [0,1); 12 levels, F=2; out [N,24] f32.
// res: 16,23,32,46,64,92,128,184,256,368,512,736; hash iff r^3>2^19
// (levels 5..11, each exactly 2^19 entries -> & 0x7FFFF). Dense: no modulo.
//
// Round-13: round-10 structure (best: mega=455us) + SC0 (device-scope)
// TABLE GATHERS via raw buffer-load intrinsics.
//   Model: mega is L1-MSHR x L2-latency bound (~422K line fills/CU at
//   ~250cyc / ~96 MSHRs = 455us). sc0 loads are device-scope -> served by
//   XCD L2 without TCP/L1 allocation (unlike r12's nt, which skipped L2
//   too: FETCH 190MB->2.6GB, mega 1199us). aux=1 == SC0 on gfx94x/95x.
//   Intrinsics (CK pattern) keep compiler vmcnt scheduling -> MLP intact.

namespace {
constexpr int NLEV = 12;
constexpr int BLOCK = 256;
constexpr int DENSE_A_END = 146368;   // levels 0..3
constexpr int L4_SIZE = 262144;       // level 4 (64^3)
constexpr unsigned P1 = 2654435761u;
constexpr unsigned P2 = 805459861u;
constexpr unsigned HMASK = (1u << 19) - 1u;

__device__ __constant__ constexpr int kRes[NLEV] = {
    16, 23, 32, 46, 64, 92, 128, 184, 256, 368, 512, 736};
__device__ __constant__ constexpr int kOff[NLEV] = {
    0, 4096, 16264, 49032, 146368, 408512,
    932800, 1457088, 1981376, 2505664, 3029952, 3554240};

typedef float    f32x2 __attribute__((ext_vector_type(2)));
typedef unsigned u32x2 __attribute__((ext_vector_type(2)));
typedef unsigned u32x4 __attribute__((ext_vector_type(4)));
typedef int      i32x4 __attribute__((ext_vector_type(4)));

__device__ __forceinline__ unsigned pkh2(float a, float b) {
    __half2 h = __floats2half2_rn(a, b);
    return *reinterpret_cast<unsigned*>(&h);
}
__device__ __forceinline__ float lo2f(unsigned u) {
    __half2 h = *reinterpret_cast<__half2*>(&u);
    return __low2float(h);
}
__device__ __forceinline__ float hi2f(unsigned u) {
    __half2 h = *reinterpret_cast<__half2*>(&u);
    return __high2float(h);
}
}  // namespace

// ---- raw buffer loads with cache-policy (CK-style intrinsic decls) ----
extern "C" __device__ unsigned
llvm_buf_ld_b32(i32x4, unsigned, unsigned, unsigned)
    __asm("llvm.amdgcn.raw.buffer.load.i32");
extern "C" __device__ u32x2
llvm_buf_ld_b64(i32x4, unsigned, unsigned, unsigned)
    __asm("llvm.amdgcn.raw.buffer.load.v2i32");
extern "C" __device__ u32x4
llvm_buf_ld_b128(i32x4, unsigned, unsigned, unsigned)
    __asm("llvm.amdgcn.raw.buffer.load.v4i32");

__device__ __forceinline__ i32x4 make_rsrc(const void* p) {
    unsigned long long a = (unsigned long long)p;
    i32x4 r;
    r.x = (int)(unsigned)(a & 0xFFFFFFFFull);
    r.y = (int)(unsigned)(a >> 32);   // stride=0
    r.z = -1;                          // num_records: bounds check off
    r.w = 0x00020000;                  // raw dword buffer
    return r;
}
// aux=1 -> SC0 (device scope: no L1 allocation, L2 cached) on gfx940+.
__device__ __forceinline__ unsigned g32(i32x4 r, unsigned byteoff) {
    return llvm_buf_ld_b32(r, byteoff, 0, 1);
}
__device__ __forceinline__ u32x2 g64(i32x4 r, unsigned byteoff) {
    return llvm_buf_ld_b64(r, byteoff, 0, 1);
}
__device__ __forceinline__ u32x4 g128(i32x4 r, unsigned byteoff) {
    return llvm_buf_ld_b128(r, byteoff, 0, 1);
}

// ---- fused pre-pass: packed (all), quad (levels 0-3), pair4 (level 4) ----
__global__ void __launch_bounds__(BLOCK)
pack_all_kernel(const float2* __restrict__ emb,
                unsigned* __restrict__ packed,
                u32x4* __restrict__ quad,
                u32x2* __restrict__ pair4, int total)
{
    int i = blockIdx.x * BLOCK + threadIdx.x;
    if (i >= total) return;
    float2 v = emb[i];
    packed[i] = pkh2(v.x, v.y);
    if (i < DENSE_A_END) {
        int R = (i < 4096) ? 16 : (i < 16264) ? 23 : (i < 49032) ? 32 : 46;
        float2 e1 = emb[i + 1];
        float2 e2 = emb[i + R];
        float2 e3 = emb[i + R + 1];
        u32x4 q;
        q.x = pkh2(v.x, v.y);   q.y = pkh2(e1.x, e1.y);
        q.z = pkh2(e2.x, e2.y); q.w = pkh2(e3.x, e3.y);
        quad[i] = q;
    }
    if (i < L4_SIZE) {
        int g = DENSE_A_END + i;
        float2 a = emb[g];
        float2 b = emb[g + 1];
        u32x2 o; o.x = pkh2(a.x, a.y); o.y = pkh2(b.x, b.y);
        pair4[i] = o;
    }
}

// ---- hash level encode; lvlbase = byte offset of level table ----
__device__ __forceinline__ unsigned
encode_hash_rt(float x, float y, float z, i32x4 rsrc, unsigned lvlbase,
               float scale)
{
    const float px = x * scale, py = y * scale, pz = z * scale;
    const float fx = floorf(px), fy = floorf(py), fz = floorf(pz);
    const float rx = px - fx, ry = py - fy, rz = pz - fz;
    const unsigned ix = (unsigned)fx, iy = (unsigned)fy, iz = (unsigned)fz;
    const unsigned yA = iy * P1, yB = yA + P1;
    const unsigned zA = iz * P2, zB = zA + P2;
    const unsigned h00 = (ix ^ yA ^ zA) & HMASK;
    const unsigned h10 = (ix ^ yB ^ zA) & HMASK;
    const unsigned h01 = (ix ^ yA ^ zB) & HMASK;
    const unsigned h11 = (ix ^ yB ^ zB) & HMASK;

    // aligned x-pair words: {h, h^1} live in one 8B-aligned u32x2
    const u32x2 q00 = g64(rsrc, lvlbase + (h00 & ~1u) * 4u);
    const u32x2 q10 = g64(rsrc, lvlbase + (h10 & ~1u) * 4u);
    const u32x2 q01 = g64(rsrc, lvlbase + (h01 & ~1u) * 4u);
    const u32x2 q11 = g64(rsrc, lvlbase + (h11 & ~1u) * 4u);

    unsigned e00 = (h00 & 1) ? q00.y : q00.x;
    unsigned e10 = (h10 & 1) ? q10.y : q10.x;
    unsigned e01 = (h01 & 1) ? q01.y : q01.x;
    unsigned e11 = (h11 & 1) ? q11.y : q11.x;
    unsigned f00 = (h00 & 1) ? q00.x : q00.y;
    unsigned f10 = (h10 & 1) ? q10.x : q10.y;
    unsigned f01 = (h01 & 1) ? q01.x : q01.y;
    unsigned f11 = (h11 & 1) ? q11.x : q11.y;

    if (ix & 1u) {  // odd ix: sibling word is ix-1; need real ix+1 entries
        const unsigned xo = ix + 1u;
        f00 = g32(rsrc, lvlbase + ((xo ^ yA ^ zA) & HMASK) * 4u);
        f10 = g32(rsrc, lvlbase + ((xo ^ yB ^ zA) & HMASK) * 4u);
        f01 = g32(rsrc, lvlbase + ((xo ^ yA ^ zB) & HMASK) * 4u);
        f11 = g32(rsrc, lvlbase + ((xo ^ yB ^ zB) & HMASK) * 4u);
    }

    const float wx0 = 1.0f - rx, wx1 = rx;
    const float wy0 = 1.0f - ry, wy1 = ry;
    const float wz0 = 1.0f - rz, wz1 = rz;
    const float w00 = wy0 * wz0, w10 = wy1 * wz0;
    const float w01 = wy0 * wz1, w11 = wy1 * wz1;
    float sx = 0.0f, sy = 0.0f;
    sx = fmaf(w00 * wx0, lo2f(e00), fmaf(w00 * wx1, lo2f(f00), sx));
    sy = fmaf(w00 * wx0, hi2f(e00), fmaf(w00 * wx1, hi2f(f00), sy));
    sx = fmaf(w10 * wx0, lo2f(e10), fmaf(w10 * wx1, lo2f(f10), sx));
    sy = fmaf(w10 * wx0, hi2f(e10), fmaf(w10 * wx1, hi2f(f10), sy));
    sx = fmaf(w01 * wx0, lo2f(e01), fmaf(w01 * wx1, lo2f(f01), sx));
    sy = fmaf(w01 * wx0, hi2f(e01), fmaf(w01 * wx1, hi2f(f01), sy));
    sx = fmaf(w11 * wx0, lo2f(e11), fmaf(w11 * wx1, lo2f(f11), sx));
    sy = fmaf(w11 * wx0, hi2f(e11), fmaf(w11 * wx1, hi2f(f11), sy));
    return pkh2(sx, sy);
}

// ---- MEGA: blocks [0,CB)=dense_a, [CB,2CB)=dense_b, [2CB,9CB)=hash5..11 ----
__global__ void __launch_bounds__(BLOCK)
mega_kernel(const float* __restrict__ inp,
            const u32x4* __restrict__ quad,
            const u32x2* __restrict__ pair4,
            const unsigned* __restrict__ packed,
            unsigned* __restrict__ stage, int N, int CB)
{
    const int b = blockIdx.x;
    const int t = b / CB;            // task id (block-uniform)
    const int chunk = b - t * CB;
    const int g = chunk * BLOCK + threadIdx.x;   // point-pair index
    const int p0 = 2 * g;
    if (p0 >= N) return;
    const bool two = (p0 + 1 < N);

    const f32x2* ip2 = reinterpret_cast<const f32x2*>(inp);
    f32x2 v0 = ip2[3 * g + 0];
    f32x2 v1, v2;
    if (two) { v1 = ip2[3 * g + 1]; v2 = ip2[3 * g + 2]; }
    else { v1.x = inp[3 * p0 + 2]; v1.y = 0.f; v2.x = 0.f; v2.y = 0.f; }
    const float X[2] = {v0.x, v1.y};
    const float Y[2] = {v0.y, v2.x};
    const float Z[2] = {v1.x, v2.y};

    if (t == 0) {
        // dense levels 0..3, sc0 quad gathers (16B entries)
        const i32x4 qr = make_rsrc(quad);
#pragma unroll
        for (int l = 0; l < 4; ++l) {
            const unsigned R = (unsigned)kRes[l];
            const unsigned R2 = R * R;
            const float scale = (float)(kRes[l] - 1);
            const unsigned lvlbase = (unsigned)kOff[l] * 16u;
            u32x2 res;
#pragma unroll
            for (int k = 0; k < 2; ++k) {
                const float px = X[k] * scale, py = Y[k] * scale,
                            pz = Z[k] * scale;
                const float fx = floorf(px), fy = floorf(py), fz = floorf(pz);
                const float rx = px - fx, ry = py - fy, rz = pz - fz;
                const unsigned ix = (unsigned)fx, iy = (unsigned)fy,
                               iz = (unsigned)fz;
                const unsigned base = ix + iy * R + iz * R2;
                const u32x4 q0 = g128(qr, lvlbase + base * 16u);
                const u32x4 q1 = g128(qr, lvlbase + (base + R2) * 16u);
                const float wx0 = 1.0f - rx, wx1 = rx;
                const float wy0 = 1.0f - ry, wy1 = ry;
                const float wz0 = 1.0f - rz, wz1 = rz;
                const float ex00 = wx0 * lo2f(q0.x) + wx1 * lo2f(q0.y);
                const float ey00 = wx0 * hi2f(q0.x) + wx1 * hi2f(q0.y);
                const float ex10 = wx0 * lo2f(q0.z) + wx1 * lo2f(q0.w);
                const float ey10 = wx0 * hi2f(q0.z) + wx1 * hi2f(q0.w);
                const float ex01 = wx0 * lo2f(q1.x) + wx1 * lo2f(q1.y);
                const float ey01 = wx0 * hi2f(q1.x) + wx1 * hi2f(q1.y);
                const float ex11 = wx0 * lo2f(q1.z) + wx1 * lo2f(q1.w);
                const float ey11 = wx0 * hi2f(q1.z) + wx1 * hi2f(q1.w);
                const float sx = wz0 * (wy0 * ex00 + wy1 * ex10) +
                                 wz1 * (wy0 * ex01 + wy1 * ex11);
                const float sy = wz0 * (wy0 * ey00 + wy1 * ey10) +
                                 wz1 * (wy0 * ey01 + wy1 * ey11);
                res[k] = pkh2(sx, sy);
            }
            if (two) {
                __builtin_nontemporal_store(
                    res,
                    reinterpret_cast<u32x2*>(&stage[(long long)l * N + p0]));
            } else {
                __builtin_nontemporal_store(res.x,
                                            &stage[(long long)l * N + p0]);
            }
        }
    } else if (t == 1) {
        // dense level 4 (64^3), sc0 pair gathers (8B entries)
        const i32x4 pr = make_rsrc(pair4);
        constexpr unsigned R = 64, R2 = 4096;
        constexpr float scale = 63.0f;
        u32x2 res;
#pragma unroll
        for (int k = 0; k < 2; ++k) {
            const float px = X[k] * scale, py = Y[k] * scale, pz = Z[k] * scale;
            const float fx = floorf(px), fy = floorf(py), fz = floorf(pz);
            const float rx = px - fx, ry = py - fy, rz = pz - fz;
            const unsigned ix = (unsigned)fx, iy = (unsigned)fy,
                           iz = (unsigned)fz;
            const unsigned base = ix + iy * R + iz * R2;
            const u32x2 q00 = g64(pr, base * 8u);
            const u32x2 q10 = g64(pr, (base + R) * 8u);
            const u32x2 q01 = g64(pr, (base + R2) * 8u);
            const u32x2 q11 = g64(pr, (base + R2 + R) * 8u);
            const float wx0 = 1.0f - rx, wx1 = rx;
            const float wy0 = 1.0f - ry, wy1 = ry;
            const float wz0 = 1.0f - rz, wz1 = rz;
            const float w00 = wy0 * wz0, w10 = wy1 * wz0;
            const float w01 = wy0 * wz1, w11 = wy1 * wz1;
            float sx = 0.0f, sy = 0.0f;
            sx = fmaf(w00 * wx0, lo2f(q00.x), fmaf(w00 * wx1, lo2f(q00.y), sx));
            sy = fmaf(w00 * wx0, hi2f(q00.x), fmaf(w00 * wx1, hi2f(q00.y), sy));
            sx = fmaf(w10 * wx0, lo2f(q10.x), fmaf(w10 * wx1, lo2f(q10.y), sx));
            sy = fmaf(w10 * wx0, hi2f(q10.x), fmaf(w10 * wx1, hi2f(q10.y), sy));
            sx = fmaf(w01 * wx0, lo2f(q01.x), fmaf(w01 * wx1, lo2f(q01.y), sx));
            sy = fmaf(w01 * wx0, hi2f(q01.x), fmaf(w01 * wx1, hi2f(q01.y), sy));
            sx = fmaf(w11 * wx0, lo2f(q11.x), fmaf(w11 * wx1, lo2f(q11.y), sx));
            sy = fmaf(w11 * wx0, hi2f(q11.x), fmaf(w11 * wx1, hi2f(q11.y), sy));
            res[k] = pkh2(sx, sy);
        }
        unsigned* s4 = stage + 4LL * N;
        if (two) {
            __builtin_nontemporal_store(res, reinterpret_cast<u32x2*>(&s4[p0]));
        } else {
            __builtin_nontemporal_store(res.x, &s4[p0]);
        }
    } else {
        // hash level L = t + 3 (t=2..8 -> L=5..11), sc0 gathers
        const int L = t + 3;
        const float scale = (float)(kRes[L] - 1);
        const i32x4 hr = make_rsrc(packed);
        const unsigned lvlbase = (unsigned)kOff[L] * 4u;
        u32x2 res;
        res.x = encode_hash_rt(X[0], Y[0], Z[0], hr, lvlbase, scale);
        res.y = two ? encode_hash_rt(X[1], Y[1], Z[1], hr, lvlbase, scale) : 0u;
        unsigned* sl = stage + (long long)L * N;
        if (two) {
            __builtin_nontemporal_store(res, reinterpret_cast<u32x2*>(&sl[p0]));
        } else {
            __builtin_nontemporal_store(res.x, &sl[p0]);
        }
    }
}

// ---- final: [12][N] fp16x2 -> [N][24] f32, LDS transpose ----
__global__ void __launch_bounds__(BLOCK)
assemble_kernel(const unsigned* __restrict__ lvl, float* __restrict__ out,
                int N)
{
    __shared__ float s_out[BLOCK * 25];
    const int t = threadIdx.x;
    const int n = blockIdx.x * BLOCK + t;

    if (n < N) {
#pragma unroll
        for (int l = 0; l < NLEV; ++l) {
            unsigned u = __builtin_nontemporal_load(&lvl[(long long)l * N + n]);
            s_out[t * 25 + 2 * l + 0] = lo2f(u);
            s_out[t * 25 + 2 * l + 1] = hi2f(u);
        }
    }
    __syncthreads();

    const long long base = (long long)blockIdx.x * (BLOCK * 24);
    const long long lim = (long long)N * 24;
#pragma unroll
    for (int k = 0; k < 24; ++k) {
        const int g = k * BLOCK + t;
        const long long gg = base + g;
        if (gg < lim) {
            const int nl = g / 24;   // magic-mul division
            const int j = g - nl * 24;
            __builtin_nontemporal_store(s_out[nl * 25 + j], &out[gg]);
        }
    }
}

// ---- fallback: fused single-kernel (ws too small for staging) ----
__global__ void __launch_bounds__(BLOCK, 4)
fused_kernel(const float* __restrict__ inp, const float2* __restrict__ table,
             float* __restrict__ out, int N)
{
    __shared__ float s_out[BLOCK * 25];
    const int t = threadIdx.x;
    const int n = blockIdx.x * BLOCK + t;

    if (n < N) {
        const float x = inp[n * 3 + 0];
        const float y = inp[n * 3 + 1];
        const float z = inp[n * 3 + 2];

#pragma unroll
        for (int l = 0; l < NLEV; ++l) {
            const int R = kRes[l];
            const bool HASH = (l >= 5);
            const float scale = (float)(R - 1);
            const float px = x * scale, py = y * scale, pz = z * scale;
            const float fx = floorf(px), fy = floorf(py), fz = floorf(pz);
            const float wx = px - fx, wy = py - fy, wz = pz - fz;
            const unsigned ix = (unsigned)fx, iy = (unsigned)fy,
                           iz = (unsigned)fz;
            unsigned x0, x1, y0, y1, z0, z1;
            if (HASH) {
                x0 = ix;      x1 = ix + 1u;
                y0 = iy * P1; y1 = y0 + P1;
                z0 = iz * P2; z1 = z0 + P2;
            } else {
                const unsigned Ru = (unsigned)R, R2 = Ru * Ru;
                x0 = ix;      x1 = ix + 1u;
                y0 = iy * Ru; y1 = y0 + Ru;
                z0 = iz * R2; z1 = z0 + R2;
            }
            unsigned idx[8];
            if (HASH) {
                idx[0] = (x0 ^ y0 ^ z0) & HMASK; idx[1] = (x1 ^ y0 ^ z0) & HMASK;
                idx[2] = (x0 ^ y1 ^ z0) & HMASK; idx[3] = (x1 ^ y1 ^ z0) & HMASK;
                idx[4] = (x0 ^ y0 ^ z1) & HMASK; idx[5] = (x1 ^ y0 ^ z1) & HMASK;
                idx[6] = (x0 ^ y1 ^ z1) & HMASK; idx[7] = (x1 ^ y1 ^ z1) & HMASK;
            } else {
                idx[0] = x0 + y0 + z0; idx[1] = x1 + y0 + z0;
                idx[2] = x0 + y1 + z0; idx[3] = x1 + y1 + z0;
                idx[4] = x0 + y0 + z1; idx[5] = x1 + y0 + z1;
                idx[6] = x0 + y1 + z1; idx[7] = x1 + y1 + z1;
            }
            const float w0x = 1.0f - wx, w0y = 1.0f - wy, w0z = 1.0f - wz;
            const float w00 = w0x * w0y, w10 = wx * w0y;
            const float w01 = w0x * wy,  w11 = wx * wy;
            const float wt[8] = {w00 * w0z, w10 * w0z, w01 * w0z, w11 * w0z,
                                 w00 * wz,  w10 * wz,  w01 * wz,  w11 * wz};
            float sx = 0.0f, sy = 0.0f;
#pragma unroll
            for (int c = 0; c < 8; ++c) {
                float2 e = table[kOff[l] + idx[c]];
                sx = fmaf(wt[c], e.x, sx);
                sy = fmaf(wt[c], e.y, sy);
            }
            s_out[t * 25 + 2 * l + 0] = sx;
            s_out[t * 25 + 2 * l + 1] = sy;
        }
    }
    __syncthreads();
    const long long base = (long long)blockIdx.x * (BLOCK * 24);
    const long long lim = (long long)N * 24;
#pragma unroll
    for (int k = 0; k < 24; ++k) {
        const int g = k * BLOCK + t;
        const long long gg = base + g;
        if (gg < lim) {
            const int nl = g / 24;
            const int j = g - nl * 24;
            out[gg] = s_out[nl * 25 + j];
        }
    }
}

extern "C" void kernel_launch(void* const* d_in, const int* in_sizes, int n_in,
                              void* d_out, int out_size, void* d_ws, size_t ws_size,
                              hipStream_t stream) {
    const float* inputs = (const float*)d_in[0];
    const float* embeddings = (const float*)d_in[1];
    // d_in[2]/d_in[3] (offsets/resolutions) are compile-time constants here.
    float* out = (float*)d_out;

    const int N = in_sizes[0] / 3;            // 2,000,000
    const int total = in_sizes[1] / 2;        // 4,078,528 table entries

    const size_t quad_bytes = (size_t)DENSE_A_END * 16;           // 2.34 MB
    const size_t pair4_bytes = (size_t)L4_SIZE * 8;               // 2.0 MB
    const size_t packed_bytes = (size_t)total * sizeof(unsigned); // 16.3 MB
    const size_t stage_bytes = (size_t)NLEV * N * sizeof(unsigned); // 96 MB

    const int ngrid = (N + BLOCK - 1) / BLOCK;

    if (ws_size >= quad_bytes + pair4_bytes + packed_bytes + stage_bytes) {
        char* w = (char*)d_ws;
        u32x4* quad = (u32x4*)w;                  w += quad_bytes;
        u32x2* pair4 = (u32x2*)w;                 w += pair4_bytes;
        unsigned* packed = (unsigned*)w;          w += packed_bytes;
        unsigned* stage = (unsigned*)w;

        pack_all_kernel<<<(total + BLOCK - 1) / BLOCK, BLOCK, 0, stream>>>(
            (const float2*)embeddings, packed, quad, pair4, total);

        const int pairs = (N + 1) / 2;
        const int CB = (pairs + BLOCK - 1) / BLOCK;   // chunks per task
        mega_kernel<<<9 * CB, BLOCK, 0, stream>>>(
            inputs, quad, pair4, packed, stage, N, CB);

        assemble_kernel<<<ngrid, BLOCK, 0, stream>>>(stage, out, N);
    } else {
        fused_kernel<<<ngrid, BLOCK, 0, stream>>>(
            inputs, (const float2*)embeddings, out, N);
    }
}